// Round 6
// baseline (602.912 us; speedup 1.0000x reference)
//
#include <hip/hip_runtime.h>
#include <hip/hip_bf16.h>

#define NQ   900
#define BB   8
#define DD   256
#define HH   8
#define DH   32
#define LL   4
#define PP   5
#define SS   21760
#define DFF  1024
#define MQ   (NQ*BB)      // 7200
#define MV   (SS*BB)      // 174080

typedef __bf16 bf16_t;
typedef __bf16 bf16x8 __attribute__((ext_vector_type(8)));
typedef __bf16 bf16x4 __attribute__((ext_vector_type(4)));
typedef float  f32x4  __attribute__((ext_vector_type(4)));

// async global->LDS 16B copy
__device__ __forceinline__ void async16(const void* g, void* l) {
  __builtin_amdgcn_global_load_lds(
      (const __attribute__((address_space(1))) unsigned int*)g,
      (__attribute__((address_space(3))) unsigned int*)l, 16, 0, 0);
}

// ---------------------------------------------------------------------------
// vgemm2: C[M,N] = A[M,256] @ W[N,256]^T + bias.  K=256 fixed, 128-col tile.
// Block = (MR*64) rows x 128 cols, 4 waves (wave owns MR*16 rows).
// W whole-K tile (64 KB) staged once; K-loop barrier-free. Each A frag feeds
// 8 MFMAs (2x the 64-col version) -> half the A-load instructions per FLOP.
// SWZ: sibling n-tiles share blk%8 (same XCD) so A is L2-shared.
// NT: nontemporal C stores.
// ---------------------------------------------------------------------------
template<typename AT, typename OT, int RELU, int SWZ, int NT, int MR>
__global__ __launch_bounds__(256) void vgemm2(
    const AT* __restrict__ A, const bf16_t* __restrict__ W,
    const float* __restrict__ bias, OT* __restrict__ C,
    int M, int N, int nt)
{
  constexpr bool AF = (sizeof(AT) == 4);
  __shared__ __align__(16) bf16_t Ws[128 * 256];   // 64 KB
  int tn, tm;
  if (SWZ) {
    int u = blockIdx.x >> 3;
    tn = u % nt;
    tm = (u / nt) * 8 + (blockIdx.x & 7);
  } else {
    tn = blockIdx.x % nt;
    tm = blockIdx.x / nt;
  }
  const int n0 = tn << 7, m0 = tm * (MR * 64);
  const int t = threadIdx.x, wave = t >> 6, lane = t & 63;
  const int lm = lane & 15, quad = lane >> 4;

  // stage W whole-K, chunk-swizzled: slot p of col holds k-chunk p^(col&31)
#pragma unroll
  for (int j = 0; j < 16; ++j) {
    int flat = j * 4096 + t * 16;
    int col = flat >> 9;
    int kc = ((flat >> 4) & 31) ^ (col & 31);
    int colg = n0 + col; if (colg >= N) colg = N - 1;
    async16(&W[(size_t)colg * 256 + kc * 8], (char*)Ws + flat);
  }
  __syncthreads();   // only barrier before K-loop

  f32x4 acc[MR][8];
#pragma unroll
  for (int i = 0; i < MR; ++i)
#pragma unroll
    for (int j = 0; j < 8; ++j) acc[i][j] = (f32x4){0.f, 0.f, 0.f, 0.f};

#pragma unroll 2
  for (int k0 = 0; k0 < 256; k0 += 32) {
    const int ki = k0 >> 3;
    bf16x8 af[MR];
#pragma unroll
    for (int mi = 0; mi < MR; ++mi) {
      int row = m0 + wave * (MR * 16) + mi * 16 + lm; if (row >= M) row = M - 1;
      if constexpr (AF) {
        const float* ap = A + (size_t)row * 256 + k0 + quad * 8;
        f32x4 lo = *(const f32x4*)ap;
        f32x4 hi = *(const f32x4*)(ap + 4);
        bf16x8 f;
#pragma unroll
        for (int j = 0; j < 4; ++j) { f[j] = (bf16_t)lo[j]; f[4 + j] = (bf16_t)hi[j]; }
        af[mi] = f;
      } else {
        af[mi] = *(const bf16x8*)&A[(size_t)row * 256 + k0 + quad * 8];
      }
    }
    bf16x8 bfr[8];
#pragma unroll
    for (int ni = 0; ni < 8; ++ni) {
      int col = ni * 16 + lm;
      int ch = (ki + quad) ^ (col & 31);
      bfr[ni] = *(const bf16x8*)&Ws[col * 256 + ch * 8];
    }
#pragma unroll
    for (int mi = 0; mi < MR; ++mi)
#pragma unroll
      for (int ni = 0; ni < 8; ++ni)
        acc[mi][ni] = __builtin_amdgcn_mfma_f32_16x16x32_bf16(af[mi], bfr[ni], acc[mi][ni], 0, 0, 0);
  }

  float bv[8];
#pragma unroll
  for (int ni = 0; ni < 8; ++ni) {
    int c = n0 + ni * 16 + lm;
    bv[ni] = (c < N) ? bias[c] : 0.f;
  }

  if constexpr (sizeof(OT) == 4) {
#pragma unroll
    for (int mi = 0; mi < MR; ++mi) {
#pragma unroll
      for (int r = 0; r < 4; ++r) {
        int row = m0 + wave * (MR * 16) + mi * 16 + quad * 4 + r;
        if (row < M) {
#pragma unroll
          for (int ni = 0; ni < 8; ++ni) {
            int col = n0 + ni * 16 + lm;
            if (col < N) {
              float v = acc[mi][ni][r] + bv[ni];
              if (RELU) v = fmaxf(v, 0.f);
              C[(size_t)row * N + col] = (OT)v;
            }
          }
        }
      }
    }
  } else {
    // bf16 out: LDS transpose (reuse Ws) for coalesced 16B stores
    __syncthreads();
    bf16_t* Os = Ws;   // MR*64 x 128 <= 64 KB
#pragma unroll
    for (int mi = 0; mi < MR; ++mi)
#pragma unroll
      for (int r = 0; r < 4; ++r) {
        int rl = wave * (MR * 16) + mi * 16 + quad * 4 + r;
#pragma unroll
        for (int ni = 0; ni < 8; ++ni) {
          float v = acc[mi][ni][r] + bv[ni];
          if (RELU) v = fmaxf(v, 0.f);
          Os[rl * 128 + ni * 16 + lm] = (bf16_t)v;
        }
      }
    __syncthreads();
#pragma unroll
    for (int i = 0; i < MR * 4; ++i) {
      int fe = i * 2048 + t * 8;
      int rl = fe >> 7, cl = fe & 127;
      int row = m0 + rl, colg = n0 + cl;
      if (row < M && colg < N) {
        bf16x8 v8 = *(const bf16x8*)&Os[fe];
        if (NT) __builtin_nontemporal_store(v8, (bf16x8*)&C[(size_t)row * N + colg]);
        else *(bf16x8*)&C[(size_t)row * N + colg] = v8;
      }
    }
  }
}

// ---------------------------------------------------------------------------
// vgemm (64-col) kept for the N=480 merged off/aw GEMM
// ---------------------------------------------------------------------------
template<typename AT, typename OT, int RELU>
__global__ __launch_bounds__(256) void vgemm(
    const AT* __restrict__ A, const bf16_t* __restrict__ W,
    const float* __restrict__ bias, OT* __restrict__ C,
    int M, int N, int nt)
{
  __shared__ __align__(16) bf16_t Ws[64 * 256];
  const int tn = blockIdx.x % nt, tm = blockIdx.x / nt;
  const int n0 = tn << 6, m0 = tm << 8;
  const int t = threadIdx.x, wave = t >> 6, lane = t & 63;
  const int lm = lane & 15, quad = lane >> 4;

#pragma unroll
  for (int j = 0; j < 8; ++j) {
    int flat = j * 4096 + t * 16;
    int col = flat >> 9;
    int kc = ((flat >> 4) & 31) ^ (col & 31);
    int colg = n0 + col; if (colg >= N) colg = N - 1;
    async16(&W[(size_t)colg * 256 + kc * 8], (char*)Ws + flat);
  }
  __syncthreads();

  f32x4 acc[4][4];
#pragma unroll
  for (int i = 0; i < 4; ++i)
#pragma unroll
    for (int j = 0; j < 4; ++j) acc[i][j] = (f32x4){0.f, 0.f, 0.f, 0.f};

#pragma unroll 2
  for (int k0 = 0; k0 < 256; k0 += 32) {
    const int ki = k0 >> 3;
    bf16x8 bfr[4];
#pragma unroll
    for (int ni = 0; ni < 4; ++ni) {
      int col = ni * 16 + lm;
      int ch = (ki + quad) ^ (col & 31);
      bfr[ni] = *(const bf16x8*)&Ws[col * 256 + ch * 8];
    }
    bf16x8 af[4];
#pragma unroll
    for (int mi = 0; mi < 4; ++mi) {
      int row = m0 + wave * 64 + mi * 16 + lm; if (row >= M) row = M - 1;
      af[mi] = *(const bf16x8*)&A[(size_t)row * 256 + k0 + quad * 8];
    }
#pragma unroll
    for (int mi = 0; mi < 4; ++mi)
#pragma unroll
      for (int ni = 0; ni < 4; ++ni)
        acc[mi][ni] = __builtin_amdgcn_mfma_f32_16x16x32_bf16(af[mi], bfr[ni], acc[mi][ni], 0, 0, 0);
  }

  float bv[4];
#pragma unroll
  for (int ni = 0; ni < 4; ++ni) {
    int c = n0 + ni * 16 + lm;
    bv[ni] = (c < N) ? bias[c] : 0.f;
  }
#pragma unroll
  for (int mi = 0; mi < 4; ++mi) {
#pragma unroll
    for (int r = 0; r < 4; ++r) {
      int row = m0 + wave * 64 + mi * 16 + quad * 4 + r;
      if (row < M) {
#pragma unroll
        for (int ni = 0; ni < 4; ++ni) {
          int col = n0 + ni * 16 + lm;
          if (col < N) {
            float v = acc[mi][ni][r] + bv[ni];
            if (RELU) v = fmaxf(v, 0.f);
            C[(size_t)row * N + col] = (OT)v;
          }
        }
      }
    }
  }
}

// ---------------------------------------------------------------------------
// m97-style GEMM for FFN2 (K=1024)
// ---------------------------------------------------------------------------
template<typename AT, int EPI, typename OT>
__global__ __launch_bounds__(256) void gemm128(
    const AT* __restrict__ A, const bf16_t* __restrict__ W,
    const float* __restrict__ bias, OT* __restrict__ C,
    int M, int N, int K, int tiles_n)
{
  __shared__ __align__(16) bf16_t As[128 * 32];
  __shared__ __align__(16) bf16_t Bs[128 * 32];
  const int tm = blockIdx.x / tiles_n;
  const int tn = blockIdx.x - tm * tiles_n;
  const int m0 = tm << 7, n0 = tn << 7;
  const int t = threadIdx.x;
  const int wave = t >> 6, lane = t & 63;
  const int wr = wave >> 1, wc = wave & 1;
  const int lm = lane & 15, kq = lane >> 4;

  f32x4 acc[4][4];
#pragma unroll
  for (int i = 0; i < 4; ++i)
#pragma unroll
    for (int j = 0; j < 4; ++j) acc[i][j] = (f32x4){0.f, 0.f, 0.f, 0.f};

  for (int k0 = 0; k0 < K; k0 += 32) {
    __syncthreads();
#pragma unroll
    for (int i = 0; i < 2; ++i) {
      int flat = i * 4096 + t * 16;
      int row = flat >> 6;
      int cl = (flat >> 4) & 3;
      int cg = cl ^ ((row >> 1) & 3);
      int grow = m0 + row; if (grow >= M) grow = M - 1;
      async16(&A[(size_t)grow * K + k0 + cg * 8], (char*)As + flat);
    }
#pragma unroll
    for (int i = 0; i < 2; ++i) {
      int flat = i * 4096 + t * 16;
      int row = flat >> 6;
      int cl = (flat >> 4) & 3;
      int cg = cl ^ ((row >> 1) & 3);
      int grow = n0 + row; if (grow >= N) grow = N - 1;
      async16(&W[(size_t)grow * K + k0 + cg * 8], (char*)Bs + flat);
    }
    __syncthreads();

    bf16x8 af[4], bfr[4];
#pragma unroll
    for (int mi = 0; mi < 4; ++mi) {
      int row = wr * 64 + mi * 16 + lm;
      int s = (row >> 1) & 3;
      af[mi] = *(const bf16x8*)((const bf16_t*)As + row * 32 + ((kq ^ s) << 3));
    }
#pragma unroll
    for (int ni = 0; ni < 4; ++ni) {
      int row = wc * 64 + ni * 16 + lm;
      int s = (row >> 1) & 3;
      bfr[ni] = *(const bf16x8*)(Bs + row * 32 + ((kq ^ s) << 3));
    }
#pragma unroll
    for (int mi = 0; mi < 4; ++mi)
#pragma unroll
      for (int ni = 0; ni < 4; ++ni)
        acc[mi][ni] = __builtin_amdgcn_mfma_f32_16x16x32_bf16(af[mi], bfr[ni], acc[mi][ni], 0, 0, 0);
  }

  const int colb = n0 + wc * 64 + lm;
  float bv[4]; bool cok[4];
#pragma unroll
  for (int ni = 0; ni < 4; ++ni) {
    int c = colb + ni * 16;
    cok[ni] = (c < N);
    bv[ni] = cok[ni] ? bias[c] : 0.f;
  }
#pragma unroll
  for (int mi = 0; mi < 4; ++mi) {
    int rbase = m0 + wr * 64 + mi * 16 + kq * 4;
#pragma unroll
    for (int reg = 0; reg < 4; ++reg) {
      int r = rbase + reg;
      if (r < M) {
#pragma unroll
        for (int ni = 0; ni < 4; ++ni) if (cok[ni]) {
          float v = acc[mi][ni][reg] + bv[ni];
          if (EPI == 1) v = fmaxf(v, 0.f);
          C[(size_t)r * N + colb + ni * 16] = (OT)v;
        }
      }
    }
  }
}

// ---------------------------------------------------------------------------
// fused weight convert (8 matrices -> bf16) + off/aw bias concat (f32)
// ---------------------------------------------------------------------------
__global__ __launch_bounds__(256) void cvt_all(
    const float* __restrict__ s0, const float* __restrict__ s1,
    const float* __restrict__ s2, const float* __restrict__ s3,
    const float* __restrict__ s4, const float* __restrict__ s5,
    const float* __restrict__ s6, const float* __restrict__ s7,
    bf16_t* __restrict__ dst,
    const float* __restrict__ ob, const float* __restrict__ ab,
    float* __restrict__ bcat)
{
  int i = blockIdx.x * 256 + threadIdx.x;
  if (i < 130048) {
    const float* s; int base;
    if (i < 24576)      { s = s0; base = 0; }
    else if (i < 32768) { s = s1; base = 24576; }
    else if (i < 43008) { s = s2; base = 32768; }
    else if (i < 48128) { s = s3; base = 43008; }
    else if (i < 56320) { s = s4; base = 48128; }
    else if (i < 64512) { s = s5; base = 56320; }
    else if (i < 97280) { s = s6; base = 64512; }
    else                { s = s7; base = 97280; }
    int li = i - base;
    f32x4 x0 = ((const f32x4*)s)[2 * li], x1 = ((const f32x4*)s)[2 * li + 1];
    bf16x8 r;
#pragma unroll
    for (int j = 0; j < 4; ++j) { r[j] = (bf16_t)x0[j]; r[4 + j] = (bf16_t)x1[j]; }
    ((bf16x8*)dst)[i] = r;
  } else {
    int j = i - 130048;
    if (j < 480) bcat[j] = (j < 320) ? ob[j] : ab[j - 320];
  }
}

__global__ __launch_bounds__(256) void addpos_kernel(
    const float* __restrict__ a, const float* __restrict__ b,
    bf16_t* __restrict__ o, int n8)
{
  int i = blockIdx.x * 256 + threadIdx.x;
  if (i < n8) {
    f32x4 x0 = ((const f32x4*)a)[2 * i], x1 = ((const f32x4*)a)[2 * i + 1];
    f32x4 y0 = ((const f32x4*)b)[2 * i], y1 = ((const f32x4*)b)[2 * i + 1];
    bf16x8 r;
#pragma unroll
    for (int j = 0; j < 4; ++j) { r[j] = (bf16_t)(x0[j] + y0[j]); r[4 + j] = (bf16_t)(x1[j] + y1[j]); }
    ((bf16x8*)o)[i] = r;
  }
}

// ---------------------------------------------------------------------------
// residual + layernorm (f32 out, optional bf16 second output), D=256
// ---------------------------------------------------------------------------
template<int WBF>
__global__ __launch_bounds__(256) void lnres_kernel(
    const float* __restrict__ x, const float* __restrict__ res,
    const float* __restrict__ g, const float* __restrict__ bta,
    float* __restrict__ out, bf16_t* __restrict__ outb, int rows)
{
  int wave = threadIdx.x >> 6, lane = threadIdx.x & 63;
  int row = blockIdx.x * 4 + wave;
  if (row >= rows) return;
  const float4* xp = (const float4*)(x + (size_t)row * DD);
  const float4* rp = (const float4*)(res + (size_t)row * DD);
  float4 v = xp[lane], rr = rp[lane];
  float a0 = v.x + rr.x, a1 = v.y + rr.y, a2 = v.z + rr.z, a3 = v.w + rr.w;
  float s = a0 + a1 + a2 + a3;
#pragma unroll
  for (int off = 32; off; off >>= 1) s += __shfl_xor(s, off);
  float mean = s * (1.0f / DD);
  float d0 = a0 - mean, d1 = a1 - mean, d2 = a2 - mean, d3 = a3 - mean;
  float vs = d0 * d0 + d1 * d1 + d2 * d2 + d3 * d3;
#pragma unroll
  for (int off = 32; off; off >>= 1) vs += __shfl_xor(vs, off);
  float inv = rsqrtf(vs * (1.0f / DD) + 1e-5f);
  float4 gg = ((const float4*)g)[lane];
  float4 bb = ((const float4*)bta)[lane];
  float o0 = d0 * inv * gg.x + bb.x, o1 = d1 * inv * gg.y + bb.y;
  float o2 = d2 * inv * gg.z + bb.z, o3 = d3 * inv * gg.w + bb.w;
  float4 o; o.x = o0; o.y = o1; o.z = o2; o.w = o3;
  ((float4*)(out + (size_t)row * DD))[lane] = o;
  if (WBF) {
    bf16x4 ob; ob[0] = (bf16_t)o0; ob[1] = (bf16_t)o1; ob[2] = (bf16_t)o2; ob[3] = (bf16_t)o3;
    ((bf16x4*)(outb + (size_t)row * DD))[lane] = ob;
  }
}

// ---------------------------------------------------------------------------
// MFMA flash self-attention. Block = (b,h) x 64-q tile.
// ---------------------------------------------------------------------------
__global__ __launch_bounds__(256) void attn_mfma(
    const bf16_t* __restrict__ qk, const bf16_t* __restrict__ vp,
    bf16_t* __restrict__ sa)
{
  __shared__ __align__(16) bf16_t Ks[128 * 32];
  __shared__ __align__(16) bf16_t VT[32 * 136];
  __shared__ __align__(16) bf16_t Pw[4][16 * 136];
  const int bh = blockIdx.x;
  const int b = bh & 7, h = bh >> 3;
  const int qt = blockIdx.y;
  const int t = threadIdx.x, wave = t >> 6, lane = t & 63;
  const int lm = lane & 15, quad = lane >> 4;
  const int q0 = qt * 64 + wave * 16;

  int qrow = q0 + lm; if (qrow > NQ - 1) qrow = NQ - 1;
  bf16x8 aqr = *(const bf16x8*)&qk[((size_t)qrow * BB + b) * 512 + h * 32 + quad * 8];
  bf16x8 aq;
#pragma unroll
  for (int j = 0; j < 8; ++j) aq[j] = (bf16_t)((float)aqr[j] * 0.17677669529663687f);

  f32x4 m_run = {-1e30f, -1e30f, -1e30f, -1e30f};
  f32x4 l_run = {0.f, 0.f, 0.f, 0.f};
  f32x4 o0 = {0.f, 0.f, 0.f, 0.f}, o1 = {0.f, 0.f, 0.f, 0.f};
  const f32x4 zero = {0.f, 0.f, 0.f, 0.f};

  for (int c = 0; c < 8; ++c) {
    const int k0 = c * 128;
    __syncthreads();
#pragma unroll
    for (int i = 0; i < 2; ++i) {
      int flat = i * 4096 + t * 16;
      int row = flat >> 6;
      int cl = (flat >> 4) & 3;
      int cg = cl ^ ((row >> 1) & 3);
      int key = k0 + row; if (key > NQ - 1) key = NQ - 1;
      async16(&qk[((size_t)key * BB + b) * 512 + 256 + h * 32 + cg * 8], (char*)Ks + flat);
    }
#pragma unroll
    for (int i = 0; i < 2; ++i) {
      int idx = t * 2 + i;
      int key = idx >> 2, dc = idx & 3;
      int gk = k0 + key;
      if (gk < NQ) {
        bf16x8 vv = *(const bf16x8*)&vp[((size_t)gk * BB + b) * 256 + h * 32 + dc * 8];
#pragma unroll
        for (int u = 0; u < 8; ++u) VT[(dc * 8 + u) * 136 + key] = vv[u];
      } else {
#pragma unroll
        for (int u = 0; u < 8; ++u) VT[(dc * 8 + u) * 136 + key] = (bf16_t)0.f;
      }
    }
    __syncthreads();

    f32x4 s[8];
#pragma unroll
    for (int blk = 0; blk < 8; ++blk) {
      int row = blk * 16 + lm;
      int sw = (row >> 1) & 3;
      bf16x8 kb = *(const bf16x8*)&Ks[row * 32 + ((quad ^ sw) << 3)];
      s[blk] = __builtin_amdgcn_mfma_f32_16x16x32_bf16(aq, kb, zero, 0, 0, 0);
    }
    if (c == 7) {
#pragma unroll
      for (int blk = 0; blk < 8; ++blk) {
        if (k0 + blk * 16 + lm >= NQ) {
#pragma unroll
          for (int r = 0; r < 4; ++r) s[blk][r] = -1e30f;
        }
      }
    }
    f32x4 mx = s[0];
#pragma unroll
    for (int blk = 1; blk < 8; ++blk)
#pragma unroll
      for (int r = 0; r < 4; ++r) mx[r] = fmaxf(mx[r], s[blk][r]);
#pragma unroll
    for (int d = 1; d < 16; d <<= 1)
#pragma unroll
      for (int r = 0; r < 4; ++r) mx[r] = fmaxf(mx[r], __shfl_xor(mx[r], d));
    f32x4 m_new, alpha;
#pragma unroll
    for (int r = 0; r < 4; ++r) {
      m_new[r] = fmaxf(m_run[r], mx[r]);
      alpha[r] = __expf(m_run[r] - m_new[r]);
    }
    f32x4 psum = {0.f, 0.f, 0.f, 0.f};
#pragma unroll
    for (int blk = 0; blk < 8; ++blk) {
#pragma unroll
      for (int r = 0; r < 4; ++r) {
        float p = __expf(s[blk][r] - m_new[r]);
        psum[r] += p;
        Pw[wave][(quad * 4 + r) * 136 + blk * 16 + lm] = (bf16_t)p;
      }
    }
#pragma unroll
    for (int d = 1; d < 16; d <<= 1)
#pragma unroll
      for (int r = 0; r < 4; ++r) psum[r] += __shfl_xor(psum[r], d);
#pragma unroll
    for (int r = 0; r < 4; ++r) {
      l_run[r] = l_run[r] * alpha[r] + psum[r];
      m_run[r] = m_new[r];
      o0[r] *= alpha[r];
      o1[r] *= alpha[r];
    }
    bf16x8 ap[4];
#pragma unroll
    for (int kc = 0; kc < 4; ++kc)
      ap[kc] = *(const bf16x8*)&Pw[wave][lm * 136 + kc * 32 + quad * 8];
#pragma unroll
    for (int kc = 0; kc < 4; ++kc) {
      bf16x8 vb0 = *(const bf16x8*)&VT[lm * 136 + kc * 32 + quad * 8];
      bf16x8 vb1 = *(const bf16x8*)&VT[(16 + lm) * 136 + kc * 32 + quad * 8];
      o0 = __builtin_amdgcn_mfma_f32_16x16x32_bf16(ap[kc], vb0, o0, 0, 0, 0);
      o1 = __builtin_amdgcn_mfma_f32_16x16x32_bf16(ap[kc], vb1, o1, 0, 0, 0);
    }
  }
#pragma unroll
  for (int r = 0; r < 4; ++r) {
    int q = q0 + quad * 4 + r;
    if (q < NQ) {
      float inv = 1.0f / l_run[r];
      size_t base = ((size_t)q * BB + b) * 256 + h * 32;
      sa[base + lm] = (bf16_t)(o0[r] * inv);
      sa[base + 16 + lm] = (bf16_t)(o1[r] * inv);
    }
  }
}

// ---------------------------------------------------------------------------
// deformable sampling: block per row r=q*8+b; reads combined oa [7200,480]
// ---------------------------------------------------------------------------
__global__ __launch_bounds__(256) void deform_kernel(
    const bf16_t* __restrict__ value, const float* __restrict__ oa,
    const float* __restrict__ refp, bf16_t* __restrict__ out)
{
  __shared__ float logits[160];
  __shared__ float wfin[160][4];
  __shared__ int   tidx[160][4];
  __shared__ float hmax[8], hsum[8];
  const int r = blockIdx.x;
  const int b = r & 7;
  const int t = threadIdx.x;
  if (t < 160) {
    int i20 = t % 20;
    int l = i20 / 5;
    logits[t] = oa[(size_t)r * 480 + 320 + t];
    float ox = oa[(size_t)r * 480 + t * 2];
    float oy = oa[(size_t)r * 480 + t * 2 + 1];
    const float* rp = refp + ((size_t)r * LL + l) * 4;
    int Wl = 128 >> l;
    int st = (l == 0) ? 0 : (l == 1) ? 16384 : (l == 2) ? 20480 : 21504;
    float lx = rp[0] + ox * 0.1f * rp[2];
    float ly = rp[1] + oy * 0.1f * rp[3];
    float xx = lx * (float)Wl - 0.5f;
    float yy = ly * (float)Wl - 0.5f;
    float x0f = floorf(xx), y0f = floorf(yy);
    float fx = xx - x0f, fy = yy - y0f;
    int x0 = (int)x0f, y0 = (int)y0f;
#pragma unroll
    for (int tap = 0; tap < 4; ++tap) {
      int dx = tap & 1, dy = tap >> 1;
      int xi = x0 + dx, yi = y0 + dy;
      float w = (dx ? fx : 1.0f - fx) * (dy ? fy : 1.0f - fy);
      bool valid = (xi >= 0) & (xi < Wl) & (yi >= 0) & (yi < Wl);
      int xc = min(max(xi, 0), Wl - 1);
      int yc = min(max(yi, 0), Wl - 1);
      tidx[t][tap] = (st + yc * Wl + xc) * BB + b;
      wfin[t][tap] = valid ? w : 0.0f;
    }
  }
  __syncthreads();
  if (t < 8) {
    float m = -1e30f;
    for (int i = 0; i < 20; ++i) m = fmaxf(m, logits[t * 20 + i]);
    float s = 0.f;
    for (int i = 0; i < 20; ++i) s += __expf(logits[t * 20 + i] - m);
    hmax[t] = m; hsum[t] = s;
  }
  __syncthreads();
  if (t < 160) {
    int h = t / 20;
    float p = __expf(logits[t] - hmax[h]) / hsum[h];
#pragma unroll
    for (int tap = 0; tap < 4; ++tap) wfin[t][tap] *= p;
  }
  __syncthreads();
  const int h = t >> 5, d = t & 31;
  const bf16_t* vbase = value + h * 32 + d;
  float acc = 0.f;
#pragma unroll 4
  for (int i = 0; i < 20; ++i) {
    int e = h * 20 + i;
#pragma unroll
    for (int tap = 0; tap < 4; ++tap) {
      float w = wfin[e][tap];
      float v = (float)vbase[(size_t)tidx[e][tap] * 256];
      acc = fmaf(w, v, acc);
    }
  }
  out[(size_t)r * 256 + t] = (bf16_t)acc;
}

// ---------------------------------------------------------------------------
// launch
// ---------------------------------------------------------------------------
static inline int tiles(int x) { return (x + 127) >> 7; }

extern "C" void kernel_launch(void* const* d_in, const int* in_sizes, int n_in,
                              void* d_out, int out_size, void* d_ws, size_t ws_size,
                              hipStream_t stream) {
  const float* tgt     = (const float*)d_in[0];
  const float* pos     = (const float*)d_in[1];
  const float* refp    = (const float*)d_in[2];
  const float* memory  = (const float*)d_in[3];
  const float* sa_in_w = (const float*)d_in[4];
  const float* sa_in_b = (const float*)d_in[5];
  const float* sa_out_w= (const float*)d_in[6];
  const float* sa_out_b= (const float*)d_in[7];
  const float* off_w   = (const float*)d_in[8];
  const float* off_b   = (const float*)d_in[9];
  const float* aw_w    = (const float*)d_in[10];
  const float* aw_b    = (const float*)d_in[11];
  const float* val_w   = (const float*)d_in[12];
  const float* val_b   = (const float*)d_in[13];
  const float* co_w    = (const float*)d_in[14];
  const float* co_b    = (const float*)d_in[15];
  const float* w1      = (const float*)d_in[16];
  const float* b1      = (const float*)d_in[17];
  const float* w2      = (const float*)d_in[18];
  const float* b2      = (const float*)d_in[19];
  const float* ln1_g   = (const float*)d_in[20];
  const float* ln1_b   = (const float*)d_in[21];
  const float* ln2_g   = (const float*)d_in[22];
  const float* ln2_b   = (const float*)d_in[23];
  const float* ln3_g   = (const float*)d_in[24];
  const float* ln3_b   = (const float*)d_in[25];

  char* ws = (char*)d_ws;
  bf16_t* value_bf = (bf16_t*)ws;                        // 89,128,960
  bf16_t* qk_bf    = (bf16_t*)(ws + 89128960);           // 7,372,800 | h1_bf 14,745,600
  bf16_t* h1_bf    = qk_bf;
  bf16_t* qsum_bf  = (bf16_t*)(ws + 103874560);          // 3,686,400
  bf16_t* vp_bf    = (bf16_t*)(ws + 107560960);          // 3,686,400
  bf16_t* sa_bf    = (bf16_t*)(ws + 111247360);          // 3,686,400
  float*  tgt2     = (float*)(ws + 114933760);           // 7,372,800
  bf16_t* query_bf = (bf16_t*)(ws + 122306560);          // 3,686,400
  float*  oa       = (float*)(ws + 125992960);           // 13,824,000 ([7200,480])
  bf16_t* ca_bf    = (bf16_t*)(ws + 139816960);          // 3,686,400
  float*  gout     = (float*)(ws + 143503360);           // 7,372,800
  float*  tgt3     = (float*)(ws + 150876160);           // 7,372,800
  bf16_t* tgt3_bf  = (bf16_t*)(ws + 158248960);          // 3,686,400
  bf16_t* wbf      = (bf16_t*)(ws + 161935360);          // 2,080,768
  bf16_t* sa_in_wb = wbf;
  bf16_t* sa_out_wb= wbf + 196608;
  bf16_t* oa_wb    = wbf + 262144;
  bf16_t* val_wb   = wbf + 385024;
  bf16_t* co_wb    = wbf + 450560;
  bf16_t* w1b      = wbf + 516096;
  bf16_t* w2b      = wbf + 778240;
  float*  oabias   = (float*)(ws + 164016128);
  float*  outp     = (float*)d_out;

  const int n8q = MQ * DD / 8;
  const int mtq = (MQ + 255) >> 8;   // 29  (256-row tiles)
  const int mt2 = (MQ + 127) >> 7;   // 57  (128-row tiles)
  const int mt1 = (MQ + 63) >> 6;    // 113 (64-row tiles)

  cvt_all<<<dim3(510), 256, 0, stream>>>(
      sa_in_w, sa_out_w, off_w, aw_w, val_w, co_w, w1, w2, wbf,
      off_b, aw_b, oabias);

  // ---- self-attention ----
  addpos_kernel<<<dim3((n8q + 255) / 256), 256, 0, stream>>>(tgt, pos, qsum_bf, n8q);
  vgemm2<bf16_t, bf16_t, 0, 0, 0, 2><<<dim3(mt2 * 4), 256, 0, stream>>>(
      qsum_bf, sa_in_wb, sa_in_b, qk_bf, MQ, 512, 4);
  vgemm2<float, bf16_t, 0, 0, 0, 1><<<dim3(mt1 * 2), 256, 0, stream>>>(
      tgt, sa_in_wb + 512 * 256, sa_in_b + 512, vp_bf, MQ, 256, 2);
  attn_mfma<<<dim3(64, 15), 256, 0, stream>>>(qk_bf, vp_bf, sa_bf);
  vgemm2<bf16_t, float, 0, 0, 0, 1><<<dim3(mt1 * 2), 256, 0, stream>>>(
      sa_bf, sa_out_wb, sa_out_b, gout, MQ, 256, 2);
  lnres_kernel<0><<<dim3((MQ + 3) / 4), 256, 0, stream>>>(
      gout, tgt, ln2_g, ln2_b, tgt2, (bf16_t*)nullptr, MQ);

  // ---- deformable cross-attention ----
  addpos_kernel<<<dim3((n8q + 255) / 256), 256, 0, stream>>>(tgt2, pos, query_bf, n8q);
  // value GEMM: 256x128 blocks, XCD-sibling swizzle (680 row tiles = 85*8), NT
  vgemm2<float, bf16_t, 0, 1, 1, 4><<<dim3(680 * 2), 256, 0, stream>>>(
      memory, val_wb, val_b, value_bf, MV, 256, 2);
  // merged offsets+aw GEMM, N=480 (64-col kernel)
  vgemm<bf16_t, float, 0><<<dim3(mtq * 8), 256, 0, stream>>>(
      query_bf, oa_wb, oabias, oa, MQ, 480, 8);
  deform_kernel<<<dim3(MQ), 256, 0, stream>>>(value_bf, oa, refp, ca_bf);
  vgemm2<bf16_t, float, 0, 0, 0, 1><<<dim3(mt1 * 2), 256, 0, stream>>>(
      ca_bf, co_wb, co_b, gout, MQ, 256, 2);
  lnres_kernel<1><<<dim3((MQ + 3) / 4), 256, 0, stream>>>(
      gout, tgt2, ln1_g, ln1_b, tgt3, tgt3_bf, MQ);

  // ---- FFN ----
  vgemm2<bf16_t, bf16_t, 1, 0, 0, 2><<<dim3(mt2 * 8), 256, 0, stream>>>(
      tgt3_bf, w1b, b1, h1_bf, MQ, 1024, 8);
  gemm128<bf16_t, 0, float><<<dim3(tiles(MQ) * 2), 256, 0, stream>>>(
      h1_bf, w2b, b2, gout, MQ, 256, DFF, 2);
  lnres_kernel<0><<<dim3((MQ + 3) / 4), 256, 0, stream>>>(
      gout, tgt3, ln3_g, ln3_b, outp, (bf16_t*)nullptr, MQ);

  (void)in_sizes; (void)n_in; (void)out_size; (void)ws_size;
}